// Round 1
// baseline (692.556 us; speedup 1.0000x reference)
//
#include <hip/hip_runtime.h>
#include <hip/hip_bf16.h>
#include <cstdint>

// Problem constants: x is (4096, 3, 4096) fp32; q/k/v are (4096, 4096).
#define N 4096
#define ROWSTRIDE 12288  // 3*4096 floats per n-index

typedef __attribute__((ext_vector_type(8))) _Float16 half8;
typedef __attribute__((ext_vector_type(4))) _Float16 half4v;
typedef __attribute__((ext_vector_type(4))) float floatx4;

// ---------------------------------------------------------------------------
// Pack q,k (fp32 strided rows) -> fp16 dense row-major
// ---------------------------------------------------------------------------
__global__ __launch_bounds__(256) void pack_qk(const float* __restrict__ x,
                                               _Float16* __restrict__ qh,
                                               _Float16* __restrict__ kh) {
    const size_t tid = (size_t)blockIdx.x * 256 + threadIdx.x;  // 4096*1024 threads
    const int i  = (int)(tid >> 10);   // row 0..4095
    const int c4 = (int)(tid & 1023);  // float4 index within 4096-wide row
    const float4* xr = (const float4*)(x + (size_t)i * ROWSTRIDE);
    float4 q = xr[c4];
    float4 k = xr[1024 + c4];
    half4v qo = {(_Float16)q.x, (_Float16)q.y, (_Float16)q.z, (_Float16)q.w};
    half4v ko = {(_Float16)k.x, (_Float16)k.y, (_Float16)k.z, (_Float16)k.w};
    *(half4v*)(qh + tid * 4) = qo;
    *(half4v*)(kh + tid * 4) = ko;
}

// ---------------------------------------------------------------------------
// v (fp32, strided rows) -> vt fp16 with vt[d][j] = v[j][d]
// ---------------------------------------------------------------------------
__global__ __launch_bounds__(256) void transpose_v(const float* __restrict__ x,
                                                   _Float16* __restrict__ vt) {
    __shared__ float tile[32][33];  // +1 pad breaks bank conflicts
    const int j0 = blockIdx.x * 32;  // v row block
    const int d0 = blockIdx.y * 32;  // v col block
    const int t  = threadIdx.x;
    const int r  = t >> 3;       // 0..31
    const int c4 = t & 7;        // 0..7 (float4 within 32 cols)
    const float4 val = *(const float4*)(x + (size_t)(j0 + r) * ROWSTRIDE + 8192 + d0 + c4 * 4);
    tile[r][c4 * 4 + 0] = val.x;
    tile[r][c4 * 4 + 1] = val.y;
    tile[r][c4 * 4 + 2] = val.z;
    tile[r][c4 * 4 + 3] = val.w;
    __syncthreads();
    half4v o = {(_Float16)tile[c4 * 4 + 0][r], (_Float16)tile[c4 * 4 + 1][r],
                (_Float16)tile[c4 * 4 + 2][r], (_Float16)tile[c4 * 4 + 3][r]};
    *(half4v*)(vt + (size_t)(d0 + r) * N + j0 + c4 * 4) = o;
}

// ---------------------------------------------------------------------------
// NT GEMM, fp16 in / fp32 out, M=N=K=4096: C[i][j] = sum_k A[i][k]*Bt[j][k]
// m97 structure: 128x128 tile, BK=32, 4 waves, 4x4 16x16x32 MFMAs per wave,
// global_load_lds width=16 staging, 2-barrier K-loop.
// ---------------------------------------------------------------------------
#define GL2LDS(g, l)                                                                     \
    __builtin_amdgcn_global_load_lds((const __attribute__((address_space(1))) void*)(g), \
                                     (__attribute__((address_space(3))) void*)(l), 16, 0, 0)

__global__ __launch_bounds__(256) void gemm_nt(const _Float16* __restrict__ A,
                                               const _Float16* __restrict__ Bt,
                                               float* __restrict__ C) {
    __shared__ _Float16 As[128 * 32];
    __shared__ _Float16 Bs[128 * 32];
    const int t    = threadIdx.x;
    const int wave = t >> 6;
    const int lane = t & 63;
    const int wr   = wave >> 1, wc = wave & 1;
    const int rowBase = blockIdx.y * 128;
    const int colBase = blockIdx.x * 128;

    floatx4 acc[4][4] = {};

    // Staging addressing: thread t loads 16B (8 halves): row = it*64 + t/4, col = (t&3)*8.
    // LDS dst must be wave-uniform (HW writes base + lane*16).
    const int ldRow = t >> 2;
    const int ldCol = (t & 3) * 8;
    const _Float16* ga0 = A  + (size_t)(rowBase + ldRow) * N + ldCol;
    const _Float16* gb0 = Bt + (size_t)(colBase + ldRow) * N + ldCol;
    _Float16* lA = &As[wave * 512];  // wave's 1KB chunk; +2048 halves for it=1
    _Float16* lB = &Bs[wave * 512];

    const int fr = lane & 15;
    const int fk = (lane >> 4) * 8;

    for (int kt = 0; kt < 128; ++kt) {
        const int k0 = kt * 32;
        __syncthreads();  // previous iter's fragments fully consumed
        GL2LDS(ga0 + k0, lA);
        GL2LDS(ga0 + k0 + (size_t)64 * N, lA + 2048);
        GL2LDS(gb0 + k0, lB);
        GL2LDS(gb0 + k0 + (size_t)64 * N, lB + 2048);
        __syncthreads();  // compiler emits vmcnt(0) drain before barrier

        half8 af[4], bf[4];
#pragma unroll
        for (int mt = 0; mt < 4; ++mt)
            af[mt] = *(half8*)&As[(wr * 64 + mt * 16 + fr) * 32 + fk];
#pragma unroll
        for (int nt = 0; nt < 4; ++nt)
            bf[nt] = *(half8*)&Bs[(wc * 64 + nt * 16 + fr) * 32 + fk];
#pragma unroll
        for (int mt = 0; mt < 4; ++mt)
#pragma unroll
            for (int nt = 0; nt < 4; ++nt)
                acc[mt][nt] = __builtin_amdgcn_mfma_f32_16x16x32_f16(af[mt], bf[nt],
                                                                     acc[mt][nt], 0, 0, 0);
    }

    // Epilogue: C/D layout col=lane&15, row=(lane>>4)*4+reg (dtype-independent, m89/m101)
    const int quad = lane >> 4;
#pragma unroll
    for (int mt = 0; mt < 4; ++mt) {
#pragma unroll
        for (int nt = 0; nt < 4; ++nt) {
#pragma unroll
            for (int r = 0; r < 4; ++r) {
                const int row = rowBase + wr * 64 + mt * 16 + quad * 4 + r;
                const int col = colBase + wc * 64 + nt * 16 + fr;
                C[(size_t)row * N + col] = acc[mt][nt][r];
            }
        }
    }
}

// ---------------------------------------------------------------------------
// Row softmax with 0.5 scale: P[i][:] = softmax(0.5*S[i][:]) as fp16
// One 256-thread block per row; 16 elements/thread held in registers.
// ---------------------------------------------------------------------------
__global__ __launch_bounds__(256) void softmax_rows(const float* __restrict__ S,
                                                    _Float16* __restrict__ P) {
    const int row = blockIdx.x;
    const int t   = threadIdx.x;
    const float4* Sr = (const float4*)(S + (size_t)row * N);

    float4 v[4];
    float lmax = -3.0e38f;
#pragma unroll
    for (int r = 0; r < 4; ++r) {
        v[r] = Sr[t + 256 * r];
        v[r].x *= 0.5f; v[r].y *= 0.5f; v[r].z *= 0.5f; v[r].w *= 0.5f;
        lmax = fmaxf(lmax, fmaxf(fmaxf(v[r].x, v[r].y), fmaxf(v[r].z, v[r].w)));
    }
#pragma unroll
    for (int off = 32; off; off >>= 1) lmax = fmaxf(lmax, __shfl_xor(lmax, off, 64));
    __shared__ float redm[4], reds[4];
    const int wave = t >> 6, lane = t & 63;
    if (lane == 0) redm[wave] = lmax;
    __syncthreads();
    const float m = fmaxf(fmaxf(redm[0], redm[1]), fmaxf(redm[2], redm[3]));

    float lsum = 0.f;
#pragma unroll
    for (int r = 0; r < 4; ++r) {
        v[r].x = __expf(v[r].x - m);
        v[r].y = __expf(v[r].y - m);
        v[r].z = __expf(v[r].z - m);
        v[r].w = __expf(v[r].w - m);
        lsum += (v[r].x + v[r].y) + (v[r].z + v[r].w);
    }
#pragma unroll
    for (int off = 32; off; off >>= 1) lsum += __shfl_xor(lsum, off, 64);
    if (lane == 0) reds[wave] = lsum;
    __syncthreads();
    const float inv = 1.0f / (((reds[0] + reds[1]) + (reds[2] + reds[3])));

#pragma unroll
    for (int r = 0; r < 4; ++r) {
        half4v o = {(_Float16)(v[r].x * inv), (_Float16)(v[r].y * inv),
                    (_Float16)(v[r].z * inv), (_Float16)(v[r].w * inv)};
        *(half4v*)(P + (size_t)row * N + (t + 256 * r) * 4) = o;
    }
}

// ---------------------------------------------------------------------------
extern "C" void kernel_launch(void* const* d_in, const int* in_sizes, int n_in,
                              void* d_out, int out_size, void* d_ws, size_t ws_size,
                              hipStream_t stream) {
    const float* x = (const float*)d_in[0];
    float* out     = (float*)d_out;
    char* ws       = (char*)d_ws;

    _Float16* qh = (_Float16*)(ws);                    // 32 MB
    _Float16* kh = (_Float16*)(ws + (32ull << 20));    // 32 MB
    _Float16* vt = (_Float16*)(ws + (64ull << 20));    // 32 MB
    float*    S  = (float*)   (ws + (96ull << 20));    // 64 MB
    _Float16* P  = qh;  // qh is dead after GEMM1; alias P over it

    pack_qk    <<<16384, 256, 0, stream>>>(x, qh, kh);
    transpose_v<<<dim3(128, 128), 256, 0, stream>>>(x, vt);
    gemm_nt    <<<dim3(32, 32), 256, 0, stream>>>(qh, kh, S);
    softmax_rows<<<4096, 256, 0, stream>>>(S, P);
    gemm_nt    <<<dim3(32, 32), 256, 0, stream>>>(P, vt, out);
}

// Round 2
// 646.262 us; speedup vs baseline: 1.0716x; 1.0716x over previous
//
#include <hip/hip_runtime.h>
#include <hip/hip_bf16.h>
#include <cstdint>

// Problem constants: x is (4096, 3, 4096) fp32; q/k/v are (4096, 4096).
#define N 4096
#define ROWSTRIDE 12288  // 3*4096 floats per n-index

typedef __attribute__((ext_vector_type(8))) _Float16 half8;
typedef __attribute__((ext_vector_type(4))) _Float16 half4v;
typedef __attribute__((ext_vector_type(4))) float floatx4;

// ---------------------------------------------------------------------------
// Pack q,k (fp32 strided rows) -> fp16 dense row-major. q is pre-scaled by 0.5
// (folds the softmax logit scale into the GEMM input).
// ---------------------------------------------------------------------------
__global__ __launch_bounds__(256) void pack_qk(const float* __restrict__ x,
                                               _Float16* __restrict__ qh,
                                               _Float16* __restrict__ kh) {
    const size_t tid = (size_t)blockIdx.x * 256 + threadIdx.x;  // 4096*1024 threads
    const int i  = (int)(tid >> 10);   // row 0..4095
    const int c4 = (int)(tid & 1023);  // float4 index within 4096-wide row
    const float4* xr = (const float4*)(x + (size_t)i * ROWSTRIDE);
    float4 q = xr[c4];
    float4 k = xr[1024 + c4];
    half4v qo = {(_Float16)(q.x * 0.5f), (_Float16)(q.y * 0.5f),
                 (_Float16)(q.z * 0.5f), (_Float16)(q.w * 0.5f)};
    half4v ko = {(_Float16)k.x, (_Float16)k.y, (_Float16)k.z, (_Float16)k.w};
    *(half4v*)(qh + tid * 4) = qo;
    *(half4v*)(kh + tid * 4) = ko;
}

// ---------------------------------------------------------------------------
// v (fp32, strided rows) -> vt fp16 with vt[d][j] = v[j][d]
// ---------------------------------------------------------------------------
__global__ __launch_bounds__(256) void transpose_v(const float* __restrict__ x,
                                                   _Float16* __restrict__ vt) {
    __shared__ float tile[32][33];  // +1 pad breaks bank conflicts
    const int j0 = blockIdx.x * 32;  // v row block
    const int d0 = blockIdx.y * 32;  // v col block
    const int t  = threadIdx.x;
    const int r  = t >> 3;       // 0..31
    const int c4 = t & 7;        // 0..7 (float4 within 32 cols)
    const float4 val = *(const float4*)(x + (size_t)(j0 + r) * ROWSTRIDE + 8192 + d0 + c4 * 4);
    tile[r][c4 * 4 + 0] = val.x;
    tile[r][c4 * 4 + 1] = val.y;
    tile[r][c4 * 4 + 2] = val.z;
    tile[r][c4 * 4 + 3] = val.w;
    __syncthreads();
    half4v o = {(_Float16)tile[c4 * 4 + 0][r], (_Float16)tile[c4 * 4 + 1][r],
                (_Float16)tile[c4 * 4 + 2][r], (_Float16)tile[c4 * 4 + 3][r]};
    *(half4v*)(vt + (size_t)(d0 + r) * N + j0 + c4 * 4) = o;
}

// ---------------------------------------------------------------------------
// NT GEMM, fp16 in / fp32 out, M=N=K=4096: C[i][j] = sum_k A[i][k]*Bt[j][k]
// m97 structure + BK=64 split into two BK=32 sub-tiles in separate LDS
// regions: halves the number of full vmcnt(0) barrier drains (64 vs 128) and
// lets ks=1 ds_reads overlap ks=0 MFMAs (no barrier between sub-passes).
// LDS = 32 KB/block (still occupancy-safe; VGPR-limited at ~3 blocks/CU).
// ---------------------------------------------------------------------------
#define GL2LDS(g, l)                                                                     \
    __builtin_amdgcn_global_load_lds((const __attribute__((address_space(1))) void*)(g), \
                                     (__attribute__((address_space(3))) void*)(l), 16, 0, 0)

__global__ __launch_bounds__(256) void gemm_nt(const _Float16* __restrict__ A,
                                               const _Float16* __restrict__ Bt,
                                               float* __restrict__ C) {
    __shared__ _Float16 As[2 * 128 * 32];  // [ks][row][k] sub-tiles
    __shared__ _Float16 Bs[2 * 128 * 32];
    const int t    = threadIdx.x;
    const int wave = t >> 6;
    const int lane = t & 63;
    const int wr   = wave >> 1, wc = wave & 1;
    const int rowBase = blockIdx.y * 128;
    const int colBase = blockIdx.x * 128;

    floatx4 acc[4][4] = {};

    // Staging: thread t loads 16B (8 halves): row = t/4 (+64), col = (t&3)*8.
    // LDS dst is wave-uniform base + lane*16 -> layout must be lane-contiguous.
    const int ldRow = t >> 2;
    const int ldCol = (t & 3) * 8;
    const _Float16* ga0 = A  + (size_t)(rowBase + ldRow) * N + ldCol;
    const _Float16* gb0 = Bt + (size_t)(colBase + ldRow) * N + ldCol;
    _Float16* lA = &As[wave * 512];  // wave's 1KB chunk within a sub-tile
    _Float16* lB = &Bs[wave * 512];

    const int fr = lane & 15;
    const int fk = (lane >> 4) * 8;

    for (int kt = 0; kt < 64; ++kt) {
        const int k0 = kt * 64;
        __syncthreads();  // previous iter's fragments fully consumed
        // ks=0 sub-tile (k0..k0+31)
        GL2LDS(ga0 + k0, lA);
        GL2LDS(ga0 + k0 + (size_t)64 * N, lA + 2048);
        GL2LDS(gb0 + k0, lB);
        GL2LDS(gb0 + k0 + (size_t)64 * N, lB + 2048);
        // ks=1 sub-tile (k0+32..k0+63)
        GL2LDS(ga0 + k0 + 32, lA + 4096);
        GL2LDS(ga0 + k0 + 32 + (size_t)64 * N, lA + 6144);
        GL2LDS(gb0 + k0 + 32, lB + 4096);
        GL2LDS(gb0 + k0 + 32 + (size_t)64 * N, lB + 6144);
        __syncthreads();  // single vmcnt(0) drain per BK=64

#pragma unroll
        for (int ks = 0; ks < 2; ++ks) {
            half8 af[4], bf[4];
#pragma unroll
            for (int mt = 0; mt < 4; ++mt)
                af[mt] = *(half8*)&As[ks * 4096 + (wr * 64 + mt * 16 + fr) * 32 + fk];
#pragma unroll
            for (int nt = 0; nt < 4; ++nt)
                bf[nt] = *(half8*)&Bs[ks * 4096 + (wc * 64 + nt * 16 + fr) * 32 + fk];
#pragma unroll
            for (int mt = 0; mt < 4; ++mt)
#pragma unroll
                for (int nt = 0; nt < 4; ++nt)
                    acc[mt][nt] = __builtin_amdgcn_mfma_f32_16x16x32_f16(af[mt], bf[nt],
                                                                         acc[mt][nt], 0, 0, 0);
        }
    }

    // Epilogue: C/D layout col=lane&15, row=(lane>>4)*4+reg (dtype-independent)
    const int quad = lane >> 4;
#pragma unroll
    for (int mt = 0; mt < 4; ++mt) {
#pragma unroll
        for (int nt = 0; nt < 4; ++nt) {
#pragma unroll
            for (int r = 0; r < 4; ++r) {
                const int row = rowBase + wr * 64 + mt * 16 + quad * 4 + r;
                const int col = colBase + wc * 64 + nt * 16 + fr;
                C[(size_t)row * N + col] = acc[mt][nt][r];
            }
        }
    }
}

// ---------------------------------------------------------------------------
// Row softmax (scale already folded into q): P[i][:] = softmax(S[i][:]) fp16
// ---------------------------------------------------------------------------
__global__ __launch_bounds__(256) void softmax_rows(const float* __restrict__ S,
                                                    _Float16* __restrict__ P) {
    const int row = blockIdx.x;
    const int t   = threadIdx.x;
    const float4* Sr = (const float4*)(S + (size_t)row * N);

    float4 v[4];
    float lmax = -3.0e38f;
#pragma unroll
    for (int r = 0; r < 4; ++r) {
        v[r] = Sr[t + 256 * r];
        lmax = fmaxf(lmax, fmaxf(fmaxf(v[r].x, v[r].y), fmaxf(v[r].z, v[r].w)));
    }
#pragma unroll
    for (int off = 32; off; off >>= 1) lmax = fmaxf(lmax, __shfl_xor(lmax, off, 64));
    __shared__ float redm[4], reds[4];
    const int wave = t >> 6, lane = t & 63;
    if (lane == 0) redm[wave] = lmax;
    __syncthreads();
    const float m = fmaxf(fmaxf(redm[0], redm[1]), fmaxf(redm[2], redm[3]));

    float lsum = 0.f;
#pragma unroll
    for (int r = 0; r < 4; ++r) {
        v[r].x = __expf(v[r].x - m);
        v[r].y = __expf(v[r].y - m);
        v[r].z = __expf(v[r].z - m);
        v[r].w = __expf(v[r].w - m);
        lsum += (v[r].x + v[r].y) + (v[r].z + v[r].w);
    }
#pragma unroll
    for (int off = 32; off; off >>= 1) lsum += __shfl_xor(lsum, off, 64);
    if (lane == 0) reds[wave] = lsum;
    __syncthreads();
    const float inv = 1.0f / (((reds[0] + reds[1]) + (reds[2] + reds[3])));

#pragma unroll
    for (int r = 0; r < 4; ++r) {
        half4v o = {(_Float16)(v[r].x * inv), (_Float16)(v[r].y * inv),
                    (_Float16)(v[r].z * inv), (_Float16)(v[r].w * inv)};
        *(half4v*)(P + (size_t)row * N + (t + 256 * r) * 4) = o;
    }
}

// ---------------------------------------------------------------------------
extern "C" void kernel_launch(void* const* d_in, const int* in_sizes, int n_in,
                              void* d_out, int out_size, void* d_ws, size_t ws_size,
                              hipStream_t stream) {
    const float* x = (const float*)d_in[0];
    float* out     = (float*)d_out;
    char* ws       = (char*)d_ws;

    _Float16* qh = (_Float16*)(ws);                    // 32 MB
    _Float16* kh = (_Float16*)(ws + (32ull << 20));    // 32 MB
    _Float16* vt = (_Float16*)(ws + (64ull << 20));    // 32 MB
    float*    S  = (float*)   (ws + (96ull << 20));    // 64 MB
    _Float16* P  = qh;  // qh is dead after GEMM1; alias P over it

    pack_qk    <<<16384, 256, 0, stream>>>(x, qh, kh);
    transpose_v<<<dim3(128, 128), 256, 0, stream>>>(x, vt);
    gemm_nt    <<<dim3(32, 32), 256, 0, stream>>>(qh, kh, S);
    softmax_rows<<<4096, 256, 0, stream>>>(S, P);
    gemm_nt    <<<dim3(32, 32), 256, 0, stream>>>(P, vt, out);
}